// Round 4
// baseline (141.552 us; speedup 1.0000x reference)
//
#include <hip/hip_runtime.h>
#include <hip/hip_bf16.h>

#define N 2048
#define FEAT 2048
#define K_NEG 10
#define NCLS 288
#define M1 0.3f
#define M2 0.3f
#define CW 0.01f

#define BM 128
#define BN 128
#define BK 64
#define NT (FEAT / BK)

typedef __attribute__((ext_vector_type(8))) __bf16 bf16x8;
typedef __attribute__((ext_vector_type(4))) float f32x4;
typedef unsigned long long u64;

__device__ __forceinline__ unsigned short f32_to_bf16(float f) {
    unsigned int u = __float_as_uint(f);
    u += 0x7fffu + ((u >> 16) & 1u);   // round-to-nearest-even
    return (unsigned short)(u >> 16);
}

__device__ __forceinline__ unsigned int rotl32(unsigned int x, int d) {
    return (x << d) | (x >> (32 - d));
}

// Exact replica of jax.random.uniform(jax.random.key(42), (2048,2048)) at flat index f.
__device__ float threefry_uniform(unsigned int f) {
    const unsigned int H = (unsigned int)(N) * (unsigned int)(N) / 2u;
    unsigned int x0, x1; int word;
    if (f < H) { x0 = f;     x1 = f + H; word = 0; }
    else       { x0 = f - H; x1 = f;     word = 1; }
    unsigned int ks[3];
    ks[0] = 0u; ks[1] = 42u; ks[2] = 0u ^ 42u ^ 0x1BD11BDAu;
    x0 += ks[0]; x1 += ks[1];
    const int rotA[4] = {13, 15, 26, 6};
    const int rotB[4] = {17, 29, 16, 24};
    #pragma unroll
    for (int i = 0; i < 5; ++i) {
        const int* r = (i & 1) ? rotB : rotA;
        #pragma unroll
        for (int j = 0; j < 4; ++j) {
            x0 += x1; x1 = rotl32(x1, r[j]); x1 ^= x0;
        }
        x0 += ks[(i + 1) % 3];
        x1 += ks[(i + 2) % 3] + (unsigned int)(i + 1);
    }
    unsigned int bits = (word == 0) ? x0 : x1;
    return __uint_as_float((bits >> 9) | 0x3f800000u) - 1.0f;
}

// async 16B global -> LDS (linear dest = wave-uniform base + lane*16)
__device__ __forceinline__ void gld16(const unsigned short* g, unsigned short* l) {
    __builtin_amdgcn_global_load_lds(
        (const __attribute__((address_space(1))) unsigned int*)g,
        (__attribute__((address_space(3))) unsigned int*)l,
        16, 0, 0);
}

// Kernel A: per-row ||x||^2 (fp32 exact), center-loss partial, fp32->bf16 convert.
__global__ void __launch_bounds__(256) prep_kernel(
        const float* __restrict__ emb, const int* __restrict__ labels,
        const float* __restrict__ centers, unsigned short* __restrict__ xbf,
        float* __restrict__ sq, float* __restrict__ centerp) {
    int i = blockIdx.x;
    int t = threadIdx.x;
    int lab = labels[i];
    const float4* erow = (const float4*)(emb + (size_t)i * FEAT);
    const float4* crow = (const float4*)(centers + (size_t)lab * FEAT);
    uint2* xrow = (uint2*)(xbf + (size_t)i * FEAT);
    float ssum = 0.f, csum = 0.f;
    #pragma unroll
    for (int p = 0; p < 2; ++p) {
        int idx4 = p * 256 + t;
        float4 e = erow[idx4];
        float4 c = crow[idx4];
        ssum += e.x*e.x + e.y*e.y + e.z*e.z + e.w*e.w;
        float dx = e.x-c.x, dy = e.y-c.y, dz = e.z-c.z, dw = e.w-c.w;
        csum += dx*dx + dy*dy + dz*dz + dw*dw;
        unsigned int w0 = (unsigned int)f32_to_bf16(e.x) | ((unsigned int)f32_to_bf16(e.y) << 16);
        unsigned int w1 = (unsigned int)f32_to_bf16(e.z) | ((unsigned int)f32_to_bf16(e.w) << 16);
        xrow[idx4] = make_uint2(w0, w1);
    }
    #pragma unroll
    for (int off = 32; off; off >>= 1) {
        ssum += __shfl_xor(ssum, off);
        csum += __shfl_xor(csum, off);
    }
    __shared__ float s1[4], s2[4];
    int lane = t & 63, w = t >> 6;
    if (lane == 0) { s1[w] = ssum; s2[w] = csum; }
    __syncthreads();
    if (t == 0) {
        sq[i]      = s1[0] + s1[1] + s1[2] + s1[3];
        centerp[i] = s2[0] + s2[1] + s2[2] + s2[3];
    }
}

// Kernel B: G = X X^T via bf16 MFMA, 2-phase pipelined, XOR-swizzled LDS.
// Swizzle (rule #21, both-sides): LDS slot (row, sd) holds global (row, sd^(row&7));
// STAGE pre-swizzles the per-lane GLOBAL source (dest stays linear for global_load_lds),
// ds_read uses slot = s ^ (row&7). Balances each b128 read across all 32 banks.
__global__ void __launch_bounds__(512) gemm_dist_kernel(
        const unsigned short* __restrict__ xbf, const float* __restrict__ sq,
        float* __restrict__ dist) {
    __shared__ __align__(16) unsigned short As[2][BM * BK];
    __shared__ __align__(16) unsigned short Bs[2][BM * BK];
    int brow0 = blockIdx.y * BM;
    int bcol0 = blockIdx.x * BN;
    int t = threadIdx.x;
    int lane = t & 63, wid = t >> 6;
    int wr = wid >> 2, wc = wid & 3;          // 2 x 4 wave grid
    f32x4 acc[4][2] = {};

    #define STAGE(buf, kelem) do {                                              \
        _Pragma("unroll")                                                       \
        for (int q = 0; q < 2; ++q) {                                           \
            int chunk = q * 512 + t;                                            \
            int row = chunk >> 3, c16 = chunk & 7;                              \
            int csrc = c16 ^ (row & 7);   /* involutive pre-swizzle */          \
            gld16(xbf + (size_t)(brow0 + row) * FEAT + (kelem) + csrc * 8,      \
                  &As[buf][chunk * 8]);                                         \
            gld16(xbf + (size_t)(bcol0 + row) * FEAT + (kelem) + csrc * 8,      \
                  &Bs[buf][chunk * 8]);                                         \
        } } while (0)

    STAGE(0, 0);
    asm volatile("s_waitcnt vmcnt(0)" ::: "memory");
    __syncthreads();

    for (int kt = 0; kt < NT; ++kt) {
        int cur = kt & 1;
        if (kt + 1 < NT) STAGE(cur ^ 1, (kt + 1) * BK);

        bf16x8 a[2][4], b[2][2];
        #pragma unroll
        for (int kk = 0; kk < 2; ++kk) {
            #pragma unroll
            for (int m = 0; m < 4; ++m) {
                int r = wr * 64 + m * 16 + (lane & 15);
                int slot = (kk * 4 + (lane >> 4)) ^ (r & 7);
                a[kk][m] = *(const bf16x8*)(&As[cur][r * BK + slot * 8]);
            }
            #pragma unroll
            for (int n = 0; n < 2; ++n) {
                int r = wc * 32 + n * 16 + (lane & 15);
                int slot = (kk * 4 + (lane >> 4)) ^ (r & 7);
                b[kk][n] = *(const bf16x8*)(&Bs[cur][r * BK + slot * 8]);
            }
        }
        #pragma unroll
        for (int m = 0; m < 4; ++m)
            #pragma unroll
            for (int n = 0; n < 2; ++n)
                #pragma unroll
                for (int kk = 0; kk < 2; ++kk)
                    acc[m][n] = __builtin_amdgcn_mfma_f32_16x16x32_bf16(a[kk][m], b[kk][n], acc[m][n], 0, 0, 0);

        asm volatile("s_waitcnt vmcnt(0)" ::: "memory");
        __syncthreads();
    }
    #undef STAGE

    // C/D layout: col = lane&15, row = (lane>>4)*4 + reg  [m89/m91]
    #pragma unroll
    for (int m = 0; m < 4; ++m) {
        int grow_base = brow0 + wr * 64 + m * 16 + (lane >> 4) * 4;
        #pragma unroll
        for (int n = 0; n < 2; ++n) {
            int gcol = bcol0 + wc * 32 + n * 16 + (lane & 15);
            float sqc = sq[gcol];
            #pragma unroll
            for (int r = 0; r < 4; ++r) {
                int grow = grow_base + r;
                float d2 = sq[grow] + sqc - 2.0f * acc[m][n][r];
                dist[(size_t)grow * N + gcol] = sqrtf(fmaxf(d2, 1e-12f));
            }
        }
    }
}

// Kernel C: per-row top-10 negatives via branch-free bitonic merge tree (16-wide
// lists, all-register merges, static indices), threefry positive pick, and per-row
// per-class minima (min1, argmin class, min2) for neg2.
// key = (float_bits(dist) << 32) | idx  -> ascending u64 == (dist asc, idx asc).
__global__ void __launch_bounds__(256) topk_kernel(
        const float* __restrict__ dist, const int* __restrict__ labels,
        float* __restrict__ d_ap, int* __restrict__ avalid,
        int* __restrict__ negs1, float* __restrict__ d_an,
        float* __restrict__ rmin1, int* __restrict__ rc1, float* __restrict__ rmin2) {
    int i = blockIdx.x;
    int t = threadIdx.x;
    int lab = labels[i];
    const float INF = __int_as_float(0x7f800000);
    const u64 PADKEY = 0xFFFFFFFFFFFFFFFFull;

    __shared__ u64 lb0[256 * 16];             // 32 KB
    __shared__ u64 lb1[128 * 16];             // 16 KB
    __shared__ unsigned int mbuck[NCLS];
    __shared__ float rv[256];
    __shared__ int   ri[256];
    __shared__ int   rc[256];
    __shared__ float rm2[256];

    for (int c = t; c < NCLS; c += 256) mbuck[c] = 0x7f800000u;
    __syncthreads();

    // Phase 1: strided scan; 8 u64 keys; threefry best; neg count; class mins.
    u64 k[8];
    float bestu = -1.0f; int bestj = 0;
    int negc = 0;
    #pragma unroll
    for (int s = 0; s < 8; ++s) {
        int j = s * 256 + t;
        float d = dist[(size_t)i * N + j];
        int lj = labels[j];
        if (j != i) atomicMin(&mbuck[lj], __float_as_uint(d));
        if (lj == lab) {
            k[s] = PADKEY;
            if (j != i) {
                float u = threefry_uniform((unsigned int)(i * N + j));
                if (u > bestu || (u == bestu && j < bestj)) { bestu = u; bestj = j; }
            }
        } else {
            k[s] = ((u64)__float_as_uint(d) << 32) | (unsigned int)j;
            negc++;
        }
    }

    // 8-element Batcher odd-even sorting network (static indices).
    #define CE(x, y) { u64 lo = k[x] < k[y] ? k[x] : k[y]; u64 hi = k[x] < k[y] ? k[y] : k[x]; k[x] = lo; k[y] = hi; }
    CE(0,1) CE(2,3) CE(4,5) CE(6,7)
    CE(0,2) CE(1,3) CE(4,6) CE(5,7)
    CE(1,2) CE(5,6)
    CE(0,4) CE(1,5) CE(2,6) CE(3,7)
    CE(2,4) CE(3,5)
    CE(1,2) CE(3,4) CE(5,6)
    #undef CE

    #pragma unroll
    for (int q = 0; q < 8; ++q) lb0[t * 16 + q] = k[q];
    #pragma unroll
    for (int q = 8; q < 16; ++q) lb0[t * 16 + q] = PADKEY;

    // reduce threefry best + neg count
    rv[t] = bestu; ri[t] = bestj; rc[t] = negc;
    __syncthreads();
    for (int s = 128; s > 0; s >>= 1) {
        if (t < s) {
            if (rv[t + s] > rv[t] || (rv[t + s] == rv[t] && ri[t + s] < ri[t])) {
                rv[t] = rv[t + s]; ri[t] = ri[t + s];
            }
            rc[t] += rc[t + s];
        }
        __syncthreads();
    }
    float bu = rv[0]; int bj = ri[0]; int nc = rc[0];

    // Phase 2: 8 merge rounds. Each: load both 16-lists to regs (independent,
    // static-indexed), half-cleaner min, bitonic-sort-16, store. No dependent LDS.
    #pragma unroll 1
    for (int r = 0; r < 8; ++r) {
        int s = 128 >> r;
        u64* src = (r & 1) ? lb1 : lb0;
        u64* dst = (r & 1) ? lb0 : lb1;
        if (t < s) {
            u64 A[16], B[16], m[16];
            #pragma unroll
            for (int q = 0; q < 16; ++q) A[q] = src[t * 16 + q];
            #pragma unroll
            for (int q = 0; q < 16; ++q) B[q] = src[(t + s) * 16 + q];
            #pragma unroll
            for (int q = 0; q < 16; ++q) {
                u64 bb = B[15 - q];
                m[q] = (A[q] < bb) ? A[q] : bb;     // 16 smallest, bitonic order
            }
            #define CEB(x, y) { if (m[x] > m[y]) { u64 tmp = m[x]; m[x] = m[y]; m[y] = tmp; } }
            CEB(0,8) CEB(1,9) CEB(2,10) CEB(3,11) CEB(4,12) CEB(5,13) CEB(6,14) CEB(7,15)
            CEB(0,4) CEB(1,5) CEB(2,6)  CEB(3,7)  CEB(8,12) CEB(9,13) CEB(10,14) CEB(11,15)
            CEB(0,2) CEB(1,3) CEB(4,6)  CEB(5,7)  CEB(8,10) CEB(9,11) CEB(12,14) CEB(13,15)
            CEB(0,1) CEB(2,3) CEB(4,5)  CEB(6,7)  CEB(8,9)  CEB(10,11) CEB(12,13) CEB(14,15)
            #undef CEB
            #pragma unroll
            for (int q = 0; q < 16; ++q) dst[t * 16 + q] = m[q];
        }
        __syncthreads();
    }
    // final list in lb0 (round 7: src lb1 -> dst lb0), list 0
    if (t < K_NEG) {
        u64 key = lb0[t];
        unsigned int hv = (unsigned int)(key >> 32);
        bool fin = hv < 0x7f800000u;
        d_an[i * K_NEG + t]  = fin ? __uint_as_float(hv) : INF;
        negs1[i * K_NEG + t] = fin ? (int)(key & 0xFFFFFFFFu) : 0;
    }
    if (t == 0) {
        bool has_pos = (bu >= 0.0f);
        avalid[i] = (has_pos && nc >= 2) ? 1 : 0;
        d_ap[i]   = has_pos ? dist[(size_t)i * N + bj] : 0.0f;
    }
    __syncthreads();

    // Phase 3: (min1, argmin-class, min2) over the 288 class buckets.
    {
        float a1 = __uint_as_float(mbuck[t]);
        int   ac = t;
        float b1 = (t < NCLS - 256) ? __uint_as_float(mbuck[256 + t]) : INF;
        int   bc = 256 + t;
        float m1v, m2v; int c1v;
        if (a1 <= b1) { m1v = a1; c1v = ac; m2v = b1; }
        else          { m1v = b1; c1v = bc; m2v = a1; }
        rv[t] = m1v; ri[t] = c1v; rm2[t] = m2v;
        __syncthreads();
        for (int s = 128; s > 0; s >>= 1) {
            if (t < s) {
                float o1 = rv[t + s]; int oc = ri[t + s]; float o2 = rm2[t + s];
                float c1m = rv[t];
                if (o1 < c1m) { rv[t] = o1; ri[t] = oc; rm2[t] = fminf(o2, c1m); }
                else          { rm2[t] = fminf(rm2[t], o1); }
            }
            __syncthreads();
        }
        if (t == 0) { rmin1[i] = rv[0]; rc1[i] = ri[0]; rmin2[i] = rm2[0]; }
    }
}

// Kernel D (cheap): per-task term from cached per-row class minima.
__global__ void __launch_bounds__(256) terms_kernel(
        const int* __restrict__ labels, const int* __restrict__ negs1,
        const float* __restrict__ d_an, const float* __restrict__ d_ap,
        const int* __restrict__ avalid, const float* __restrict__ rmin1,
        const int* __restrict__ rc1, const float* __restrict__ rmin2,
        float* __restrict__ terms, float* __restrict__ validf) {
    int task = blockIdx.x * 256 + threadIdx.x;
    if (task >= N * K_NEG) return;
    int i = task / K_NEG;
    int n1 = negs1[task];
    int lab = labels[i];
    const float INF = __int_as_float(0x7f800000);
    float dn2 = (rc1[n1] == lab) ? rmin2[n1] : rmin1[n1];
    float dan = d_an[task];
    float dap = d_ap[i];
    float t1 = fmaxf(dap - dan + M1, 0.0f);
    float t2 = fmaxf(dap - dn2 + M2, 0.0f);
    bool valid = (avalid[i] != 0) && (dan < INF) && (dn2 < INF);
    terms[task]  = valid ? (t1 + t2) : 0.0f;
    validf[task] = valid ? 1.0f : 0.0f;
}

// Kernel E: deterministic final reduction.
__global__ void __launch_bounds__(256) finalize_kernel(
        const float* __restrict__ terms, const float* __restrict__ validf,
        const float* __restrict__ centerp, float* __restrict__ out) {
    int t = threadIdx.x;
    float ts = 0.f, vs = 0.f, cs = 0.f;
    for (int j = t; j < N * K_NEG; j += 256) { ts += terms[j]; vs += validf[j]; }
    for (int j = t; j < N; j += 256) cs += centerp[j];
    __shared__ float a[256], b[256], c[256];
    a[t] = ts; b[t] = vs; c[t] = cs;
    __syncthreads();
    for (int s = 128; s > 0; s >>= 1) {
        if (t < s) { a[t] += a[t + s]; b[t] += b[t + s]; c[t] += c[t + s]; }
        __syncthreads();
    }
    if (t == 0) {
        float quad = (b[0] > 0.0f) ? (a[0] / b[0]) : 0.0f;
        out[0] = quad + CW * (c[0] / (float)N);
    }
}

extern "C" void kernel_launch(void* const* d_in, const int* in_sizes, int n_in,
                              void* d_out, int out_size, void* d_ws, size_t ws_size,
                              hipStream_t stream) {
    const float* emb     = (const float*)d_in[0];
    const int*   labels  = (const int*)d_in[1];
    const float* centers = (const float*)d_in[2];
    float* out = (float*)d_out;

    char* ws = (char*)d_ws;
    unsigned short* xbf = (unsigned short*)ws;                 // 8 MB
    float* dist = (float*)(ws + (size_t)8 * 1024 * 1024);      // 16 MB
    char* p = ws + (size_t)24 * 1024 * 1024;
    float* sq      = (float*)p; p += N * 4;
    float* centerp = (float*)p; p += N * 4;
    float* d_ap    = (float*)p; p += N * 4;
    int*   avalid  = (int*)p;   p += N * 4;
    float* rmin1   = (float*)p; p += N * 4;
    int*   rc1     = (int*)p;   p += N * 4;
    float* rmin2   = (float*)p; p += N * 4;
    int*   negs1   = (int*)p;   p += N * K_NEG * 4;
    float* d_an    = (float*)p; p += N * K_NEG * 4;
    float* terms   = (float*)p; p += N * K_NEG * 4;
    float* validf  = (float*)p; p += N * K_NEG * 4;

    prep_kernel<<<N, 256, 0, stream>>>(emb, labels, centers, xbf, sq, centerp);
    dim3 g(N / BN, N / BM);
    gemm_dist_kernel<<<g, 512, 0, stream>>>(xbf, sq, dist);
    topk_kernel<<<N, 256, 0, stream>>>(dist, labels, d_ap, avalid, negs1, d_an,
                                       rmin1, rc1, rmin2);
    terms_kernel<<<(N * K_NEG + 255) / 256, 256, 0, stream>>>(
        labels, negs1, d_an, d_ap, avalid, rmin1, rc1, rmin2, terms, validf);
    finalize_kernel<<<1, 256, 0, stream>>>(terms, validf, centerp, out);
}

// Round 5
// 115.857 us; speedup vs baseline: 1.2218x; 1.2218x over previous
//
#include <hip/hip_runtime.h>
#include <hip/hip_bf16.h>

#define N 2048
#define FEAT 2048
#define K_NEG 10
#define NCLS 288
#define M1 0.3f
#define M2 0.3f
#define CW 0.01f

#define BM 128
#define BN 128
#define BK 64
#define NT (FEAT / BK)
#define LSTR 11   // u64 stride per top-k list: odd => bank-conflict-free b64 access

typedef __attribute__((ext_vector_type(8))) __bf16 bf16x8;
typedef __attribute__((ext_vector_type(4))) float f32x4;
typedef unsigned long long u64;

__device__ __forceinline__ unsigned short f32_to_bf16(float f) {
    unsigned int u = __float_as_uint(f);
    u += 0x7fffu + ((u >> 16) & 1u);   // round-to-nearest-even
    return (unsigned short)(u >> 16);
}

__device__ __forceinline__ unsigned int rotl32(unsigned int x, int d) {
    return (x << d) | (x >> (32 - d));
}

// Exact replica of jax.random.uniform(jax.random.key(42), (2048,2048)) at flat index f.
__device__ float threefry_uniform(unsigned int f) {
    const unsigned int H = (unsigned int)(N) * (unsigned int)(N) / 2u;
    unsigned int x0, x1; int word;
    if (f < H) { x0 = f;     x1 = f + H; word = 0; }
    else       { x0 = f - H; x1 = f;     word = 1; }
    unsigned int ks[3];
    ks[0] = 0u; ks[1] = 42u; ks[2] = 0u ^ 42u ^ 0x1BD11BDAu;
    x0 += ks[0]; x1 += ks[1];
    const int rotA[4] = {13, 15, 26, 6};
    const int rotB[4] = {17, 29, 16, 24};
    #pragma unroll
    for (int i = 0; i < 5; ++i) {
        const int* r = (i & 1) ? rotB : rotA;
        #pragma unroll
        for (int j = 0; j < 4; ++j) {
            x0 += x1; x1 = rotl32(x1, r[j]); x1 ^= x0;
        }
        x0 += ks[(i + 1) % 3];
        x1 += ks[(i + 2) % 3] + (unsigned int)(i + 1);
    }
    unsigned int bits = (word == 0) ? x0 : x1;
    return __uint_as_float((bits >> 9) | 0x3f800000u) - 1.0f;
}

// async 16B global -> LDS (linear dest = wave-uniform base + lane*16)
__device__ __forceinline__ void gld16(const unsigned short* g, unsigned short* l) {
    __builtin_amdgcn_global_load_lds(
        (const __attribute__((address_space(1))) unsigned int*)g,
        (__attribute__((address_space(3))) unsigned int*)l,
        16, 0, 0);
}

// Kernel A: per-row ||x||^2 (fp32 exact), center-loss partial, fp32->bf16 convert.
__global__ void __launch_bounds__(256) prep_kernel(
        const float* __restrict__ emb, const int* __restrict__ labels,
        const float* __restrict__ centers, unsigned short* __restrict__ xbf,
        float* __restrict__ sq, float* __restrict__ centerp) {
    int i = blockIdx.x;
    int t = threadIdx.x;
    int lab = labels[i];
    const float4* erow = (const float4*)(emb + (size_t)i * FEAT);
    const float4* crow = (const float4*)(centers + (size_t)lab * FEAT);
    uint2* xrow = (uint2*)(xbf + (size_t)i * FEAT);
    float ssum = 0.f, csum = 0.f;
    #pragma unroll
    for (int p = 0; p < 2; ++p) {
        int idx4 = p * 256 + t;
        float4 e = erow[idx4];
        float4 c = crow[idx4];
        ssum += e.x*e.x + e.y*e.y + e.z*e.z + e.w*e.w;
        float dx = e.x-c.x, dy = e.y-c.y, dz = e.z-c.z, dw = e.w-c.w;
        csum += dx*dx + dy*dy + dz*dz + dw*dw;
        unsigned int w0 = (unsigned int)f32_to_bf16(e.x) | ((unsigned int)f32_to_bf16(e.y) << 16);
        unsigned int w1 = (unsigned int)f32_to_bf16(e.z) | ((unsigned int)f32_to_bf16(e.w) << 16);
        xrow[idx4] = make_uint2(w0, w1);
    }
    #pragma unroll
    for (int off = 32; off; off >>= 1) {
        ssum += __shfl_xor(ssum, off);
        csum += __shfl_xor(csum, off);
    }
    __shared__ float s1[4], s2[4];
    int lane = t & 63, w = t >> 6;
    if (lane == 0) { s1[w] = ssum; s2[w] = csum; }
    __syncthreads();
    if (t == 0) {
        sq[i]      = s1[0] + s1[1] + s1[2] + s1[3];
        centerp[i] = s2[0] + s2[1] + s2[2] + s2[3];
    }
}

// Kernel B: G = X X^T via bf16 MFMA, 2-phase pipelined, XOR-swizzled LDS.
__global__ void __launch_bounds__(512) gemm_dist_kernel(
        const unsigned short* __restrict__ xbf, const float* __restrict__ sq,
        float* __restrict__ dist) {
    __shared__ __align__(16) unsigned short As[2][BM * BK];
    __shared__ __align__(16) unsigned short Bs[2][BM * BK];
    int brow0 = blockIdx.y * BM;
    int bcol0 = blockIdx.x * BN;
    int t = threadIdx.x;
    int lane = t & 63, wid = t >> 6;
    int wr = wid >> 2, wc = wid & 3;          // 2 x 4 wave grid
    f32x4 acc[4][2] = {};

    #define STAGE(buf, kelem) do {                                              \
        _Pragma("unroll")                                                       \
        for (int q = 0; q < 2; ++q) {                                           \
            int chunk = q * 512 + t;                                            \
            int row = chunk >> 3, c16 = chunk & 7;                              \
            int csrc = c16 ^ (row & 7);   /* involutive pre-swizzle */          \
            gld16(xbf + (size_t)(brow0 + row) * FEAT + (kelem) + csrc * 8,      \
                  &As[buf][chunk * 8]);                                         \
            gld16(xbf + (size_t)(bcol0 + row) * FEAT + (kelem) + csrc * 8,      \
                  &Bs[buf][chunk * 8]);                                         \
        } } while (0)

    STAGE(0, 0);
    asm volatile("s_waitcnt vmcnt(0)" ::: "memory");
    __syncthreads();

    for (int kt = 0; kt < NT; ++kt) {
        int cur = kt & 1;
        if (kt + 1 < NT) STAGE(cur ^ 1, (kt + 1) * BK);

        bf16x8 a[2][4], b[2][2];
        #pragma unroll
        for (int kk = 0; kk < 2; ++kk) {
            #pragma unroll
            for (int m = 0; m < 4; ++m) {
                int r = wr * 64 + m * 16 + (lane & 15);
                int slot = (kk * 4 + (lane >> 4)) ^ (r & 7);
                a[kk][m] = *(const bf16x8*)(&As[cur][r * BK + slot * 8]);
            }
            #pragma unroll
            for (int n = 0; n < 2; ++n) {
                int r = wc * 32 + n * 16 + (lane & 15);
                int slot = (kk * 4 + (lane >> 4)) ^ (r & 7);
                b[kk][n] = *(const bf16x8*)(&Bs[cur][r * BK + slot * 8]);
            }
        }
        #pragma unroll
        for (int m = 0; m < 4; ++m)
            #pragma unroll
            for (int n = 0; n < 2; ++n)
                #pragma unroll
                for (int kk = 0; kk < 2; ++kk)
                    acc[m][n] = __builtin_amdgcn_mfma_f32_16x16x32_bf16(a[kk][m], b[kk][n], acc[m][n], 0, 0, 0);

        asm volatile("s_waitcnt vmcnt(0)" ::: "memory");
        __syncthreads();
    }
    #undef STAGE

    // C/D layout: col = lane&15, row = (lane>>4)*4 + reg  [m89/m91]
    #pragma unroll
    for (int m = 0; m < 4; ++m) {
        int grow_base = brow0 + wr * 64 + m * 16 + (lane >> 4) * 4;
        #pragma unroll
        for (int n = 0; n < 2; ++n) {
            int gcol = bcol0 + wc * 32 + n * 16 + (lane & 15);
            float sqc = sq[gcol];
            #pragma unroll
            for (int r = 0; r < 4; ++r) {
                int grow = grow_base + r;
                float d2 = sq[grow] + sqc - 2.0f * acc[m][n][r];
                dist[(size_t)grow * N + gcol] = sqrtf(fmaxf(d2, 1e-12f));
            }
        }
    }
}

// Kernel C: per-row top-10 negatives via branch-free bitonic merge tree.
// Lists are 10 valid u64 keys at LDS stride LSTR=11 u64 (odd => b64 accesses hit
// the 32-bank floor, no conflicts); pad-to-16 happens in registers only.
// key = (float_bits(dist) << 32) | idx  -> ascending u64 == (dist asc, idx asc).
__global__ void __launch_bounds__(256) topk_kernel(
        const float* __restrict__ dist, const int* __restrict__ labels,
        float* __restrict__ d_ap, int* __restrict__ avalid,
        int* __restrict__ negs1, float* __restrict__ d_an,
        float* __restrict__ rmin1, int* __restrict__ rc1, float* __restrict__ rmin2) {
    int i = blockIdx.x;
    int t = threadIdx.x;
    int lab = labels[i];
    const float INF = __int_as_float(0x7f800000);
    const u64 PADKEY = 0xFFFFFFFFFFFFFFFFull;

    __shared__ u64 lb0[256 * LSTR];           // 22528 B
    __shared__ u64 lb1[128 * LSTR];           // 11264 B
    __shared__ unsigned int mbuck[NCLS];
    __shared__ float rv[256];
    __shared__ int   ri[256];
    __shared__ int   rc[256];
    __shared__ float rm2[256];

    for (int c = t; c < NCLS; c += 256) mbuck[c] = 0x7f800000u;
    __syncthreads();

    // Phase 1: strided scan; 8 u64 keys; threefry best; neg count; class mins.
    u64 k[8];
    float bestu = -1.0f; int bestj = 0;
    int negc = 0;
    #pragma unroll
    for (int s = 0; s < 8; ++s) {
        int j = s * 256 + t;
        float d = dist[(size_t)i * N + j];
        int lj = labels[j];
        unsigned int db = __float_as_uint(d);
        if (j != i && db < mbuck[lj]) atomicMin(&mbuck[lj], db);  // monotone: racy pre-read safe
        if (lj == lab) {
            k[s] = PADKEY;
            if (j != i) {
                float u = threefry_uniform((unsigned int)(i * N + j));
                if (u > bestu || (u == bestu && j < bestj)) { bestu = u; bestj = j; }
            }
        } else {
            k[s] = ((u64)db << 32) | (unsigned int)j;
            negc++;
        }
    }

    // 8-element Batcher odd-even sorting network (static indices).
    #define CE(x, y) { u64 lo = k[x] < k[y] ? k[x] : k[y]; u64 hi = k[x] < k[y] ? k[y] : k[x]; k[x] = lo; k[y] = hi; }
    CE(0,1) CE(2,3) CE(4,5) CE(6,7)
    CE(0,2) CE(1,3) CE(4,6) CE(5,7)
    CE(1,2) CE(5,6)
    CE(0,4) CE(1,5) CE(2,6) CE(3,7)
    CE(2,4) CE(3,5)
    CE(1,2) CE(3,4) CE(5,6)
    #undef CE

    #pragma unroll
    for (int q = 0; q < 8; ++q) lb0[t * LSTR + q] = k[q];
    lb0[t * LSTR + 8] = PADKEY;
    lb0[t * LSTR + 9] = PADKEY;

    // reduce threefry best + neg count
    rv[t] = bestu; ri[t] = bestj; rc[t] = negc;
    __syncthreads();
    for (int s = 128; s > 0; s >>= 1) {
        if (t < s) {
            if (rv[t + s] > rv[t] || (rv[t + s] == rv[t] && ri[t + s] < ri[t])) {
                rv[t] = rv[t + s]; ri[t] = ri[t + s];
            }
            rc[t] += rc[t + s];
        }
        __syncthreads();
    }
    float bu = rv[0]; int bj = ri[0]; int nc = rc[0];

    // Phase 2: 8 merge rounds. Load both 10-lists to regs (independent, static-
    // indexed), half-cleaner vs reg-padded 16, bitonic clean, store 10.
    #pragma unroll 1
    for (int r = 0; r < 8; ++r) {
        int s = 128 >> r;
        u64* src = (r & 1) ? lb1 : lb0;
        u64* dst = (r & 1) ? lb0 : lb1;
        if (t < s) {
            u64 A[10], B[10], m[16];
            #pragma unroll
            for (int q = 0; q < 10; ++q) A[q] = src[t * LSTR + q];
            #pragma unroll
            for (int q = 0; q < 10; ++q) B[q] = src[(t + s) * LSTR + q];
            // half-cleaner of [A,PAD*6] vs [B,PAD*6]: m[q]=min(A[q],B[15-q])
            m[0] = A[0]; m[1] = A[1]; m[2] = A[2]; m[3] = A[3]; m[4] = A[4]; m[5] = A[5];
            m[6] = (A[6] < B[9]) ? A[6] : B[9];
            m[7] = (A[7] < B[8]) ? A[7] : B[8];
            m[8] = (A[8] < B[7]) ? A[8] : B[7];
            m[9] = (A[9] < B[6]) ? A[9] : B[6];
            m[10] = B[5]; m[11] = B[4]; m[12] = B[3]; m[13] = B[2]; m[14] = B[1]; m[15] = B[0];
            // 4-stage bitonic clean (valid for bitonic input)
            #define CEB(x, y) { if (m[x] > m[y]) { u64 tmp = m[x]; m[x] = m[y]; m[y] = tmp; } }
            CEB(0,8) CEB(1,9) CEB(2,10) CEB(3,11) CEB(4,12) CEB(5,13) CEB(6,14) CEB(7,15)
            CEB(0,4) CEB(1,5) CEB(2,6)  CEB(3,7)  CEB(8,12) CEB(9,13) CEB(10,14) CEB(11,15)
            CEB(0,2) CEB(1,3) CEB(4,6)  CEB(5,7)  CEB(8,10) CEB(9,11) CEB(12,14) CEB(13,15)
            CEB(0,1) CEB(2,3) CEB(4,5)  CEB(6,7)  CEB(8,9)  CEB(10,11) CEB(12,13) CEB(14,15)
            #undef CEB
            #pragma unroll
            for (int q = 0; q < 10; ++q) dst[t * LSTR + q] = m[q];
        }
        __syncthreads();
    }
    // final list in lb0 (round 7: src lb1 -> dst lb0), list 0
    if (t < K_NEG) {
        u64 key = lb0[t];
        unsigned int hv = (unsigned int)(key >> 32);
        bool fin = hv < 0x7f800000u;
        d_an[i * K_NEG + t]  = fin ? __uint_as_float(hv) : INF;
        negs1[i * K_NEG + t] = fin ? (int)(key & 0xFFFFFFFFu) : 0;
    }
    if (t == 0) {
        bool has_pos = (bu >= 0.0f);
        avalid[i] = (has_pos && nc >= 2) ? 1 : 0;
        d_ap[i]   = has_pos ? dist[(size_t)i * N + bj] : 0.0f;
    }
    __syncthreads();

    // Phase 3: (min1, argmin-class, min2) over the 288 class buckets.
    {
        float a1 = __uint_as_float(mbuck[t]);
        int   ac = t;
        float b1 = (t < NCLS - 256) ? __uint_as_float(mbuck[256 + t]) : INF;
        int   bc = 256 + t;
        float m1v, m2v; int c1v;
        if (a1 <= b1) { m1v = a1; c1v = ac; m2v = b1; }
        else          { m1v = b1; c1v = bc; m2v = a1; }
        rv[t] = m1v; ri[t] = c1v; rm2[t] = m2v;
        __syncthreads();
        for (int s = 128; s > 0; s >>= 1) {
            if (t < s) {
                float o1 = rv[t + s]; int oc = ri[t + s]; float o2 = rm2[t + s];
                float c1m = rv[t];
                if (o1 < c1m) { rv[t] = o1; ri[t] = oc; rm2[t] = fminf(o2, c1m); }
                else          { rm2[t] = fminf(rm2[t], o1); }
            }
            __syncthreads();
        }
        if (t == 0) { rmin1[i] = rv[0]; rc1[i] = ri[0]; rmin2[i] = rm2[0]; }
    }
}

// Kernel D (cheap): per-task term from cached per-row class minima.
__global__ void __launch_bounds__(256) terms_kernel(
        const int* __restrict__ labels, const int* __restrict__ negs1,
        const float* __restrict__ d_an, const float* __restrict__ d_ap,
        const int* __restrict__ avalid, const float* __restrict__ rmin1,
        const int* __restrict__ rc1, const float* __restrict__ rmin2,
        float* __restrict__ terms, float* __restrict__ validf) {
    int task = blockIdx.x * 256 + threadIdx.x;
    if (task >= N * K_NEG) return;
    int i = task / K_NEG;
    int n1 = negs1[task];
    int lab = labels[i];
    const float INF = __int_as_float(0x7f800000);
    float dn2 = (rc1[n1] == lab) ? rmin2[n1] : rmin1[n1];
    float dan = d_an[task];
    float dap = d_ap[i];
    float t1 = fmaxf(dap - dan + M1, 0.0f);
    float t2 = fmaxf(dap - dn2 + M2, 0.0f);
    bool valid = (avalid[i] != 0) && (dan < INF) && (dn2 < INF);
    terms[task]  = valid ? (t1 + t2) : 0.0f;
    validf[task] = valid ? 1.0f : 0.0f;
}

// Kernel E: deterministic final reduction.
__global__ void __launch_bounds__(256) finalize_kernel(
        const float* __restrict__ terms, const float* __restrict__ validf,
        const float* __restrict__ centerp, float* __restrict__ out) {
    int t = threadIdx.x;
    float ts = 0.f, vs = 0.f, cs = 0.f;
    for (int j = t; j < N * K_NEG; j += 256) { ts += terms[j]; vs += validf[j]; }
    for (int j = t; j < N; j += 256) cs += centerp[j];
    __shared__ float a[256], b[256], c[256];
    a[t] = ts; b[t] = vs; c[t] = cs;
    __syncthreads();
    for (int s = 128; s > 0; s >>= 1) {
        if (t < s) { a[t] += a[t + s]; b[t] += b[t + s]; c[t] += c[t + s]; }
        __syncthreads();
    }
    if (t == 0) {
        float quad = (b[0] > 0.0f) ? (a[0] / b[0]) : 0.0f;
        out[0] = quad + CW * (c[0] / (float)N);
    }
}

extern "C" void kernel_launch(void* const* d_in, const int* in_sizes, int n_in,
                              void* d_out, int out_size, void* d_ws, size_t ws_size,
                              hipStream_t stream) {
    const float* emb     = (const float*)d_in[0];
    const int*   labels  = (const int*)d_in[1];
    const float* centers = (const float*)d_in[2];
    float* out = (float*)d_out;

    char* ws = (char*)d_ws;
    unsigned short* xbf = (unsigned short*)ws;                 // 8 MB
    float* dist = (float*)(ws + (size_t)8 * 1024 * 1024);      // 16 MB
    char* p = ws + (size_t)24 * 1024 * 1024;
    float* sq      = (float*)p; p += N * 4;
    float* centerp = (float*)p; p += N * 4;
    float* d_ap    = (float*)p; p += N * 4;
    int*   avalid  = (int*)p;   p += N * 4;
    float* rmin1   = (float*)p; p += N * 4;
    int*   rc1     = (int*)p;   p += N * 4;
    float* rmin2   = (float*)p; p += N * 4;
    int*   negs1   = (int*)p;   p += N * K_NEG * 4;
    float* d_an    = (float*)p; p += N * K_NEG * 4;
    float* terms   = (float*)p; p += N * K_NEG * 4;
    float* validf  = (float*)p; p += N * K_NEG * 4;

    prep_kernel<<<N, 256, 0, stream>>>(emb, labels, centers, xbf, sq, centerp);
    dim3 g(N / BN, N / BM);
    gemm_dist_kernel<<<g, 512, 0, stream>>>(xbf, sq, dist);
    topk_kernel<<<N, 256, 0, stream>>>(dist, labels, d_ap, avalid, negs1, d_an,
                                       rmin1, rc1, rmin2);
    terms_kernel<<<(N * K_NEG + 255) / 256, 256, 0, stream>>>(
        labels, negs1, d_an, d_ap, avalid, rmin1, rc1, rmin2, terms, validf);
    finalize_kernel<<<1, 256, 0, stream>>>(terms, validf, centerp, out);
}